// Round 1
// baseline (205.271 us; speedup 1.0000x reference)
//
#include <hip/hip_runtime.h>
#include <hip/hip_bf16.h>

typedef __attribute__((ext_vector_type(8))) __bf16 bf16x8;
typedef __attribute__((ext_vector_type(4))) float f32x4;

#define D    256
#define FF   1024
#define NTOK 2048   // 8*16*16

__device__ __forceinline__ float ldf(const void* p, int i, bool isf32){
  return isf32 ? ((const float*)p)[i] : (float)(((const __bf16*)p)[i]);
}

// ---------------- stage x (fp32) + norm weights/biases (fp32) ----------------
struct MiscArgs { const void* x; const void* vec[6]; };

__global__ __launch_bounds__(256) void stage_misc_kernel(MiscArgs a, float* __restrict__ X,
                                                         float* __restrict__ VEC,
                                                         const unsigned int* __restrict__ tagp){
  bool isf32 = (*tagp == 0x3F800000u);
  const int total = NTOK*D + 6*D;
  for (int e = blockIdx.x*256 + threadIdx.x; e < total; e += gridDim.x*256){
    if (e < NTOK*D) X[e] = ldf(a.x, e, isf32);
    else { int i = e - NTOK*D; VEC[i] = ldf(a.vec[i >> 8], i & 255, isf32); }
  }
}

// ---------------- transpose + bf16-cast all weights: W[K][N] -> Wt[N][K] ----------------
// Wt region layout (elements): WqT 0, WkT 65536, WvT 131072, WoT 196608,
//                              W1T 262144, W2T 524288, W3T 786432. total 1048576.
struct TPArgs { const void* src[7]; };

__global__ __launch_bounds__(256) void transpose_w_kernel(TPArgs a, __bf16* __restrict__ WT,
                                                          const unsigned int* __restrict__ tagp){
  bool isf32 = (*tagp == 0x3F800000u);
  for (int e = blockIdx.x*256 + threadIdx.x; e < 1048576; e += gridDim.x*256){
    int wsel, local, lk, N;
    if (e < 262144){ wsel = e >> 16; local = e & 65535; lk = 8; N = 256; }
    else {
      int e2 = e - 262144; int big = e2 >> 18;
      wsel = 4 + big; local = e2 & 262143;
      if (big < 2){ lk = 8; N = 1024; } else { lk = 10; N = 256; }
    }
    int k = local & ((1 << lk) - 1), n = local >> lk;
    WT[e] = (__bf16)ldf(a.src[wsel], k*N + n, isf32);
  }
}

// ---------------- rmsnorm: one block per token, bf16 out ----------------
__global__ __launch_bounds__(256) void rmsnorm_kernel(const float* __restrict__ x,
                                                      const float* __restrict__ w,
                                                      __bf16* __restrict__ out){
  int tok = blockIdx.x, tid = threadIdx.x;
  int idx = tok*D + tid;
  float xv = x[idx];
  float s = xv*xv;
  #pragma unroll
  for (int d = 32; d > 0; d >>= 1) s += __shfl_xor(s, d, 64);
  __shared__ float red[4];
  if ((tid & 63) == 0) red[tid >> 6] = s;
  __syncthreads();
  float tot = red[0]+red[1]+red[2]+red[3];
  out[idx] = (__bf16)(xv * rsqrtf(tot*(1.0f/D) + 1e-6f) * w[tid]);
}

// ---------------- MFMA GEMM core: 64x64 tile, BK=64, A[M][K] bf16, B[N][K] bf16 ----------------
typedef __bf16 ldsrow[72];   // +8 pad: row stride 144 B, 16B-aligned, <=2-way bank alias

__device__ __forceinline__ void gemm_core(const __bf16* __restrict__ A,
                                          const __bf16* __restrict__ B,
                                          int K, int m0, int n0,
                                          ldsrow* As, ldsrow* Bs,
                                          f32x4 acc[2][2]){
  int tid = threadIdx.x;
  int wave = tid >> 6, lane = tid & 63;
  int wrow = wave & 1, wcol = wave >> 1;
  int q = lane >> 4, ln = lane & 15;
  for (int k0 = 0; k0 < K; k0 += 64){
    #pragma unroll
    for (int j = 0; j < 2; j++){
      int c = j*256 + tid;
      int row = c >> 3, seg = c & 7;
      *(float4*)&As[row][seg*8] = *(const float4*)&A[(m0+row)*K + k0 + seg*8];
      *(float4*)&Bs[row][seg*8] = *(const float4*)&B[(n0+row)*K + k0 + seg*8];
    }
    __syncthreads();
    #pragma unroll
    for (int ks = 0; ks < 2; ks++){
      bf16x8 a0 = *(const bf16x8*)&As[wrow*32      + ln][ks*32 + q*8];
      bf16x8 a1 = *(const bf16x8*)&As[wrow*32 + 16 + ln][ks*32 + q*8];
      bf16x8 b0 = *(const bf16x8*)&Bs[wcol*32      + ln][ks*32 + q*8];
      bf16x8 b1 = *(const bf16x8*)&Bs[wcol*32 + 16 + ln][ks*32 + q*8];
      acc[0][0] = __builtin_amdgcn_mfma_f32_16x16x32_bf16(a0, b0, acc[0][0], 0, 0, 0);
      acc[0][1] = __builtin_amdgcn_mfma_f32_16x16x32_bf16(a0, b1, acc[0][1], 0, 0, 0);
      acc[1][0] = __builtin_amdgcn_mfma_f32_16x16x32_bf16(a1, b0, acc[1][0], 0, 0, 0);
      acc[1][1] = __builtin_amdgcn_mfma_f32_16x16x32_bf16(a1, b1, acc[1][1], 0, 0, 0);
    }
    __syncthreads();
  }
}

#define GEMM_PROLOGUE \
  int tid = threadIdx.x; \
  int wave = tid >> 6, lane = tid & 63; \
  int wrow = wave & 1, wcol = wave >> 1; \
  int q = lane >> 4, ln = lane & 15; \
  (void)tid; \
  f32x4 acc[2][2]; \
  acc[0][0] = (f32x4){0,0,0,0}; acc[0][1] = (f32x4){0,0,0,0}; \
  acc[1][0] = (f32x4){0,0,0,0}; acc[1][1] = (f32x4){0,0,0,0};

// ---------------- fused QKV: virtual N = 768, fp32 out (+bias) ----------------
__global__ __launch_bounds__(256) void qkv_kernel(const __bf16* __restrict__ xn,
                                                  const __bf16* __restrict__ WT,
                                                  const float* __restrict__ VEC,
                                                  float* __restrict__ QKV){
  __shared__ __align__(16) __bf16 As[64][72];
  __shared__ __align__(16) __bf16 Bs[64][72];
  int m0 = blockIdx.x*64;
  int sel = blockIdx.y >> 2, n0 = (blockIdx.y & 3)*64;
  const __bf16* B = WT + sel*65536;
  const float* bias = VEC + 512 + sel*256;
  float* O = QKV + sel*(NTOK*D);
  GEMM_PROLOGUE
  gemm_core(xn, B, D, m0, n0, As, Bs, acc);
  #pragma unroll
  for (int c = 0; c < 2; c++){
    int col = n0 + wcol*32 + c*16 + ln;
    float bv = bias[col];
    #pragma unroll
    for (int r = 0; r < 2; r++){
      #pragma unroll
      for (int i = 0; i < 4; i++){
        int m = m0 + wrow*32 + r*16 + q*4 + i;
        O[m*D + col] = acc[r][c][i] + bv;
      }
    }
  }
}

// ---------------- NATTEN 3D attention: phase-split (scores -> softmax -> PV) ----------------
// One block per token; 8 heads x 32 lanes. Phase 1 computes all scores with
// batched *independent* butterfly reduces (5 neighbors at a time), phase 2 does
// ONE softmax over the whole row (4 exps/thread instead of ~188), phase 3 is a
// pure accumulation with broadcast LDS P-reads and coalesced V-loads.
__global__ __launch_bounds__(256) void attn_kernel(const float* __restrict__ qb,
                                                   const float* __restrict__ kb,
                                                   const float* __restrict__ vb,
                                                   __bf16* __restrict__ attn){
  int tok = blockIdx.x;
  int wcoord = tok & 15, hcoord = (tok >> 4) & 15, tcoord = tok >> 8;
  int g = threadIdx.x >> 5;      // head
  int lane = threadIdx.x & 31;   // dim within head
  int gofs = g*32 + lane;
  float qd = qb[tok*D + gofs];

  int h0 = min(max(hcoord-2,0), 11);
  int w0 = min(max(wcoord-2,0), 11);
  int tlo = max(tcoord-4, 0);
  int nn = (tcoord - tlo + 1) * 25;   // valid neighbor count (25..125)

  __shared__ float sS[8][128];        // per-head score row (then P row)

  // ---- phase 1: all scores; 5 independent partials per (tp,dh) batch ----
  int m = 0;
  for (int tp = tlo; tp <= tcoord; tp++){
    int tb = tp << 8;
    #pragma unroll
    for (int dh = 0; dh < 5; dh++){
      int rb = (tb + (h0+dh)*16 + w0)*D + gofs;
      float sp0 = qd * kb[rb      ];
      float sp1 = qd * kb[rb +   D];
      float sp2 = qd * kb[rb + 2*D];
      float sp3 = qd * kb[rb + 3*D];
      float sp4 = qd * kb[rb + 4*D];
      #pragma unroll
      for (int d2 = 16; d2 > 0; d2 >>= 1){
        sp0 += __shfl_xor(sp0, d2, 32);
        sp1 += __shfl_xor(sp1, d2, 32);
        sp2 += __shfl_xor(sp2, d2, 32);
        sp3 += __shfl_xor(sp3, d2, 32);
        sp4 += __shfl_xor(sp4, d2, 32);
      }
      if (lane == 0){
        sS[g][m+0] = sp0; sS[g][m+1] = sp1; sS[g][m+2] = sp2;
        sS[g][m+3] = sp3; sS[g][m+4] = sp4;
      }
      m += 5;
    }
  }
  __syncthreads();

  // ---- phase 2: one softmax over nn scores (4 entries per thread) ----
  const float sc = 0.17677669529663687f;   // 1/sqrt(32)
  float sv0 = (lane      < nn) ? sS[g][lane      ]*sc : -INFINITY;
  float sv1 = (lane + 32 < nn) ? sS[g][lane + 32 ]*sc : -INFINITY;
  float sv2 = (lane + 64 < nn) ? sS[g][lane + 64 ]*sc : -INFINITY;
  float sv3 = (lane + 96 < nn) ? sS[g][lane + 96 ]*sc : -INFINITY;
  float mx = fmaxf(fmaxf(sv0, sv1), fmaxf(sv2, sv3));
  #pragma unroll
  for (int d2 = 16; d2 > 0; d2 >>= 1) mx = fmaxf(mx, __shfl_xor(mx, d2, 32));
  float p0 = __expf(sv0 - mx), p1 = __expf(sv1 - mx);
  float p2 = __expf(sv2 - mx), p3 = __expf(sv3 - mx);
  float ps = p0 + p1 + p2 + p3;
  #pragma unroll
  for (int d2 = 16; d2 > 0; d2 >>= 1) ps += __shfl_xor(ps, d2, 32);
  float inv = 1.0f / ps;                   // fold 1/sum into P
  __syncthreads();
  if (lane      < nn) sS[g][lane      ] = p0*inv;
  if (lane + 32 < nn) sS[g][lane + 32 ] = p1*inv;
  if (lane + 64 < nn) sS[g][lane + 64 ] = p2*inv;
  if (lane + 96 < nn) sS[g][lane + 96 ] = p3*inv;
  __syncthreads();

  // ---- phase 3: PV accumulation, broadcast P reads + coalesced V loads ----
  float acc0 = 0.0f, acc1 = 0.0f;
  m = 0;
  for (int tp = tlo; tp <= tcoord; tp++){
    int tb = tp << 8;
    #pragma unroll
    for (int dh = 0; dh < 5; dh++){
      int rb = (tb + (h0+dh)*16 + w0)*D + gofs;
      acc0 += sS[g][m+0] * vb[rb      ];
      acc1 += sS[g][m+1] * vb[rb +   D];
      acc0 += sS[g][m+2] * vb[rb + 2*D];
      acc1 += sS[g][m+3] * vb[rb + 3*D];
      acc0 += sS[g][m+4] * vb[rb + 4*D];
      m += 5;
    }
  }
  attn[tok*D + gofs] = (__bf16)(acc0 + acc1);
}

// ---------------- o-proj + bias + residual(X fp32) -> h fp32 ----------------
__global__ __launch_bounds__(256) void oproj_kernel(const __bf16* __restrict__ A,
                                                    const __bf16* __restrict__ WoT,
                                                    const float* __restrict__ VEC,
                                                    const float* __restrict__ X,
                                                    float* __restrict__ h){
  __shared__ __align__(16) __bf16 As[64][72];
  __shared__ __align__(16) __bf16 Bs[64][72];
  int m0 = blockIdx.x*64, n0 = blockIdx.y*64;
  GEMM_PROLOGUE
  gemm_core(A, WoT, D, m0, n0, As, Bs, acc);
  #pragma unroll
  for (int c = 0; c < 2; c++){
    int col = n0 + wcol*32 + c*16 + ln;
    float bv = VEC[1280 + col];
    #pragma unroll
    for (int r = 0; r < 2; r++){
      #pragma unroll
      for (int i = 0; i < 4; i++){
        int m = m0 + wrow*32 + r*16 + q*4 + i;
        int idx = m*D + col;
        h[idx] = acc[r][c][i] + bv + X[idx];
      }
    }
  }
}

// ---------------- FFN up: ffh = silu(y@w1) * (y@w2), bf16 out ----------------
__global__ __launch_bounds__(256) void ffn1_kernel(const __bf16* __restrict__ y,
                                                   const __bf16* __restrict__ W1T,
                                                   const __bf16* __restrict__ W2T,
                                                   __bf16* __restrict__ ffh){
  __shared__ __align__(16) __bf16 As [64][72];
  __shared__ __align__(16) __bf16 B1s[64][72];
  __shared__ __align__(16) __bf16 B2s[64][72];
  int m0 = blockIdx.x*64, n0 = blockIdx.y*64;
  int tid = threadIdx.x;
  int wave = tid >> 6, lane = tid & 63;
  int wrow = wave & 1, wcol = wave >> 1;
  int q = lane >> 4, ln = lane & 15;
  f32x4 acc1[2][2], acc2[2][2];
  #pragma unroll
  for (int r = 0; r < 2; r++)
    #pragma unroll
    for (int c = 0; c < 2; c++){ acc1[r][c] = (f32x4){0,0,0,0}; acc2[r][c] = (f32x4){0,0,0,0}; }

  for (int k0 = 0; k0 < D; k0 += 64){
    #pragma unroll
    for (int j = 0; j < 2; j++){
      int c = j*256 + tid;
      int row = c >> 3, seg = c & 7;
      *(float4*)&As [row][seg*8] = *(const float4*)&y  [(m0+row)*D + k0 + seg*8];
      *(float4*)&B1s[row][seg*8] = *(const float4*)&W1T[(n0+row)*D + k0 + seg*8];
      *(float4*)&B2s[row][seg*8] = *(const float4*)&W2T[(n0+row)*D + k0 + seg*8];
    }
    __syncthreads();
    #pragma unroll
    for (int ks = 0; ks < 2; ks++){
      bf16x8 a0 = *(const bf16x8*)&As [wrow*32      + ln][ks*32 + q*8];
      bf16x8 a1 = *(const bf16x8*)&As [wrow*32 + 16 + ln][ks*32 + q*8];
      bf16x8 p0 = *(const bf16x8*)&B1s[wcol*32      + ln][ks*32 + q*8];
      bf16x8 p1 = *(const bf16x8*)&B1s[wcol*32 + 16 + ln][ks*32 + q*8];
      bf16x8 u0 = *(const bf16x8*)&B2s[wcol*32      + ln][ks*32 + q*8];
      bf16x8 u1 = *(const bf16x8*)&B2s[wcol*32 + 16 + ln][ks*32 + q*8];
      acc1[0][0] = __builtin_amdgcn_mfma_f32_16x16x32_bf16(a0, p0, acc1[0][0], 0,0,0);
      acc1[0][1] = __builtin_amdgcn_mfma_f32_16x16x32_bf16(a0, p1, acc1[0][1], 0,0,0);
      acc1[1][0] = __builtin_amdgcn_mfma_f32_16x16x32_bf16(a1, p0, acc1[1][0], 0,0,0);
      acc1[1][1] = __builtin_amdgcn_mfma_f32_16x16x32_bf16(a1, p1, acc1[1][1], 0,0,0);
      acc2[0][0] = __builtin_amdgcn_mfma_f32_16x16x32_bf16(a0, u0, acc2[0][0], 0,0,0);
      acc2[0][1] = __builtin_amdgcn_mfma_f32_16x16x32_bf16(a0, u1, acc2[0][1], 0,0,0);
      acc2[1][0] = __builtin_amdgcn_mfma_f32_16x16x32_bf16(a1, u0, acc2[1][0], 0,0,0);
      acc2[1][1] = __builtin_amdgcn_mfma_f32_16x16x32_bf16(a1, u1, acc2[1][1], 0,0,0);
    }
    __syncthreads();
  }
  #pragma unroll
  for (int c = 0; c < 2; c++){
    int col = n0 + wcol*32 + c*16 + ln;
    #pragma unroll
    for (int r = 0; r < 2; r++){
      #pragma unroll
      for (int i = 0; i < 4; i++){
        int m = m0 + wrow*32 + r*16 + q*4 + i;
        float g = acc1[r][c][i], u = acc2[r][c][i];
        float sig = 1.0f / (1.0f + __expf(-g));
        ffh[m*FF + col] = (__bf16)(g * sig * u);
      }
    }
  }
}

// ---------------- FFN down + residual + final store (dtype-branching) ----------------
__global__ __launch_bounds__(256) void ffn2_kernel(const __bf16* __restrict__ ffh,
                                                   const __bf16* __restrict__ W3T,
                                                   const float* __restrict__ h,
                                                   const unsigned int* __restrict__ tagp,
                                                   void* __restrict__ outp){
  __shared__ __align__(16) __bf16 As[64][72];
  __shared__ __align__(16) __bf16 Bs[64][72];
  int m0 = blockIdx.x*64, n0 = blockIdx.y*64;
  GEMM_PROLOGUE
  gemm_core(ffh, W3T, FF, m0, n0, As, Bs, acc);
  bool isf32 = (*tagp == 0x3F800000u);
  #pragma unroll
  for (int c = 0; c < 2; c++){
    int col = n0 + wcol*32 + c*16 + ln;
    #pragma unroll
    for (int r = 0; r < 2; r++){
      #pragma unroll
      for (int i = 0; i < 4; i++){
        int m = m0 + wrow*32 + r*16 + q*4 + i;
        int idx = m*D + col;
        float val = acc[r][c][i] + h[idx];
        if (isf32) ((float*)outp)[idx] = val;
        else       ((__bf16*)outp)[idx] = (__bf16)val;
      }
    }
  }
}

// ---------------- launcher ----------------
extern "C" void kernel_launch(void* const* d_in, const int* in_sizes, int n_in,
                              void* d_out, int out_size, void* d_ws, size_t ws_size,
                              hipStream_t stream){
  char* ws = (char*)d_ws;
  // byte layout
  float*  X    = (float*)(ws);                       // 2 MB
  float*  VEC  = (float*)(ws + 2097152);             // 6 KB (pad to 8 KB)
  __bf16* WT   = (__bf16*)(ws + 2097152 + 8192);     // 2 MB
  __bf16* XN   = (__bf16*)(ws + 4202496);            // 1 MB
  float*  QKV  = (float*)(ws + 5251072);             // 6 MB (q,k,v)
  __bf16* ATT  = (__bf16*)(ws + 11542528);           // 1 MB
  float*  Hb   = (float*)(ws + 12591104);            // 2 MB
  __bf16* Yb   = (__bf16*)(ws + 14688256);           // 1 MB
  __bf16* FFH  = (__bf16*)QKV;                       // reuse qkv region (4 MB) after attention

  const unsigned int* tagp = (const unsigned int*)d_in[1];

  MiscArgs ma;
  ma.x = d_in[0];
  ma.vec[0] = d_in[1]; ma.vec[1] = d_in[2]; ma.vec[2] = d_in[4];
  ma.vec[3] = d_in[6]; ma.vec[4] = d_in[8]; ma.vec[5] = d_in[10];

  TPArgs ta;
  ta.src[0] = d_in[3];  ta.src[1] = d_in[5];  ta.src[2] = d_in[7];
  ta.src[3] = d_in[9];  ta.src[4] = d_in[11]; ta.src[5] = d_in[12];
  ta.src[6] = d_in[13];

  stage_misc_kernel<<<2054, 256, 0, stream>>>(ma, X, VEC, tagp);
  transpose_w_kernel<<<4096, 256, 0, stream>>>(ta, WT, tagp);
  rmsnorm_kernel<<<NTOK, 256, 0, stream>>>(X, VEC, XN);
  qkv_kernel<<<dim3(NTOK/64, 12), 256, 0, stream>>>(XN, WT, VEC, QKV);
  attn_kernel<<<NTOK, 256, 0, stream>>>(QKV, QKV + NTOK*D, QKV + 2*NTOK*D, ATT);
  oproj_kernel<<<dim3(NTOK/64, 4), 256, 0, stream>>>(ATT, WT + 196608, VEC, X, Hb);
  rmsnorm_kernel<<<NTOK, 256, 0, stream>>>(Hb, VEC + 256, Yb);
  ffn1_kernel<<<dim3(NTOK/64, 16), 256, 0, stream>>>(Yb, WT + 262144, WT + 524288, FFH);
  ffn2_kernel<<<dim3(NTOK/64, 4), 256, 0, stream>>>(FFH, WT + 786432, Hb, tagp, d_out);
}

// Round 2
// 165.677 us; speedup vs baseline: 1.2390x; 1.2390x over previous
//
#include <hip/hip_runtime.h>
#include <hip/hip_bf16.h>

typedef __attribute__((ext_vector_type(8))) __bf16 bf16x8;
typedef __attribute__((ext_vector_type(4))) __bf16 bf16x4;
typedef __attribute__((ext_vector_type(4))) short shortx4;
typedef __attribute__((ext_vector_type(4))) float f32x4;

#define D    256
#define FF   1024
#define NTOK 2048   // 8*16*16

__device__ __forceinline__ float ldf(const void* p, int i, bool isf32){
  return isf32 ? ((const float*)p)[i] : (float)(((const __bf16*)p)[i]);
}

// K=16 bf16 MFMA wrapper (builtin name differs across ROCm versions)
__device__ __forceinline__ f32x4 mfma16x16x16bf16(bf16x4 a, bf16x4 b, f32x4 c){
#if __has_builtin(__builtin_amdgcn_mfma_f32_16x16x16_bf16)
  return __builtin_amdgcn_mfma_f32_16x16x16_bf16(a, b, c, 0, 0, 0);
#elif __has_builtin(__builtin_amdgcn_mfma_f32_16x16x16bf16_1k)
  return __builtin_amdgcn_mfma_f32_16x16x16bf16_1k(__builtin_bit_cast(shortx4, a),
                                                   __builtin_bit_cast(shortx4, b), c, 0, 0, 0);
#else
  asm volatile("v_mfma_f32_16x16x16_bf16 %0, %1, %2, %0" : "+v"(c) : "v"(a), "v"(b));
  return c;
#endif
}

// ---------------- stage x (fp32) + norm weights/biases (fp32) ----------------
struct MiscArgs { const void* x; const void* vec[6]; };

__global__ __launch_bounds__(256) void stage_misc_kernel(MiscArgs a, float* __restrict__ X,
                                                         float* __restrict__ VEC,
                                                         const unsigned int* __restrict__ tagp){
  bool isf32 = (*tagp == 0x3F800000u);
  const int total = NTOK*D + 6*D;
  for (int e = blockIdx.x*256 + threadIdx.x; e < total; e += gridDim.x*256){
    if (e < NTOK*D) X[e] = ldf(a.x, e, isf32);
    else { int i = e - NTOK*D; VEC[i] = ldf(a.vec[i >> 8], i & 255, isf32); }
  }
}

// ---------------- transpose + bf16-cast all weights: W[K][N] -> Wt[N][K] ----------------
struct TPArgs { const void* src[7]; };

__global__ __launch_bounds__(256) void transpose_w_kernel(TPArgs a, __bf16* __restrict__ WT,
                                                          const unsigned int* __restrict__ tagp){
  bool isf32 = (*tagp == 0x3F800000u);
  for (int e = blockIdx.x*256 + threadIdx.x; e < 1048576; e += gridDim.x*256){
    int wsel, local, lk, N;
    if (e < 262144){ wsel = e >> 16; local = e & 65535; lk = 8; N = 256; }
    else {
      int e2 = e - 262144; int big = e2 >> 18;
      wsel = 4 + big; local = e2 & 262143;
      if (big < 2){ lk = 8; N = 1024; } else { lk = 10; N = 256; }
    }
    int k = local & ((1 << lk) - 1), n = local >> lk;
    WT[e] = (__bf16)ldf(a.src[wsel], k*N + n, isf32);
  }
}

// ---------------- rmsnorm: one block per token, bf16 out ----------------
__global__ __launch_bounds__(256) void rmsnorm_kernel(const float* __restrict__ x,
                                                      const float* __restrict__ w,
                                                      __bf16* __restrict__ out){
  int tok = blockIdx.x, tid = threadIdx.x;
  int idx = tok*D + tid;
  float xv = x[idx];
  float s = xv*xv;
  #pragma unroll
  for (int d = 32; d > 0; d >>= 1) s += __shfl_xor(s, d, 64);
  __shared__ float red[4];
  if ((tid & 63) == 0) red[tid >> 6] = s;
  __syncthreads();
  float tot = red[0]+red[1]+red[2]+red[3];
  out[idx] = (__bf16)(xv * rsqrtf(tot*(1.0f/D) + 1e-6f) * w[tid]);
}

// ---------------- MFMA GEMM core: 64x64 tile, BK=64, A[M][K] bf16, B[N][K] bf16 ----------------
typedef __bf16 ldsrow[72];   // +8 pad

__device__ __forceinline__ void gemm_core(const __bf16* __restrict__ A,
                                          const __bf16* __restrict__ B,
                                          int K, int m0, int n0,
                                          ldsrow* As, ldsrow* Bs,
                                          f32x4 acc[2][2]){
  int tid = threadIdx.x;
  int wave = tid >> 6, lane = tid & 63;
  int wrow = wave & 1, wcol = wave >> 1;
  int q = lane >> 4, ln = lane & 15;
  for (int k0 = 0; k0 < K; k0 += 64){
    #pragma unroll
    for (int j = 0; j < 2; j++){
      int c = j*256 + tid;
      int row = c >> 3, seg = c & 7;
      *(float4*)&As[row][seg*8] = *(const float4*)&A[(m0+row)*K + k0 + seg*8];
      *(float4*)&Bs[row][seg*8] = *(const float4*)&B[(n0+row)*K + k0 + seg*8];
    }
    __syncthreads();
    #pragma unroll
    for (int ks = 0; ks < 2; ks++){
      bf16x8 a0 = *(const bf16x8*)&As[wrow*32      + ln][ks*32 + q*8];
      bf16x8 a1 = *(const bf16x8*)&As[wrow*32 + 16 + ln][ks*32 + q*8];
      bf16x8 b0 = *(const bf16x8*)&Bs[wcol*32      + ln][ks*32 + q*8];
      bf16x8 b1 = *(const bf16x8*)&Bs[wcol*32 + 16 + ln][ks*32 + q*8];
      acc[0][0] = __builtin_amdgcn_mfma_f32_16x16x32_bf16(a0, b0, acc[0][0], 0, 0, 0);
      acc[0][1] = __builtin_amdgcn_mfma_f32_16x16x32_bf16(a0, b1, acc[0][1], 0, 0, 0);
      acc[1][0] = __builtin_amdgcn_mfma_f32_16x16x32_bf16(a1, b0, acc[1][0], 0, 0, 0);
      acc[1][1] = __builtin_amdgcn_mfma_f32_16x16x32_bf16(a1, b1, acc[1][1], 0, 0, 0);
    }
    __syncthreads();
  }
}

#define GEMM_PROLOGUE \
  int tid = threadIdx.x; \
  int wave = tid >> 6, lane = tid & 63; \
  int wrow = wave & 1, wcol = wave >> 1; \
  int q = lane >> 4, ln = lane & 15; \
  (void)tid; \
  f32x4 acc[2][2]; \
  acc[0][0] = (f32x4){0,0,0,0}; acc[0][1] = (f32x4){0,0,0,0}; \
  acc[1][0] = (f32x4){0,0,0,0}; acc[1][1] = (f32x4){0,0,0,0};

// ---------------- fused QKV: virtual N = 768, bf16 out (+bias) ----------------
// sel 0 -> Qb[tok][256] bf16 ; sel 1 -> Kb[tok][256] bf16 ; sel 2 -> VT[256][2048] bf16 (transposed)
__global__ __launch_bounds__(256) void qkv_kernel(const __bf16* __restrict__ xn,
                                                  const __bf16* __restrict__ WT,
                                                  const float* __restrict__ VEC,
                                                  __bf16* __restrict__ Qb,
                                                  __bf16* __restrict__ Kb,
                                                  __bf16* __restrict__ VTb){
  __shared__ __align__(16) __bf16 As[64][72];
  __shared__ __align__(16) __bf16 Bs[64][72];
  int m0 = blockIdx.x*64;
  int sel = blockIdx.y >> 2, n0 = (blockIdx.y & 3)*64;
  const __bf16* B = WT + sel*65536;
  const float* bias = VEC + 512 + sel*256;
  GEMM_PROLOGUE
  gemm_core(xn, B, D, m0, n0, As, Bs, acc);
  if (sel < 2){
    __bf16* O = (sel == 0) ? Qb : Kb;
    #pragma unroll
    for (int c = 0; c < 2; c++){
      int col = n0 + wcol*32 + c*16 + ln;
      float bv = bias[col];
      #pragma unroll
      for (int r = 0; r < 2; r++){
        #pragma unroll
        for (int i = 0; i < 4; i++){
          int m = m0 + wrow*32 + r*16 + q*4 + i;
          O[m*D + col] = (__bf16)(acc[r][c][i] + bv);
        }
      }
    }
  } else {
    // V transposed: VT[col][m], pack 4 consecutive m into one 8B store
    #pragma unroll
    for (int c = 0; c < 2; c++){
      int col = n0 + wcol*32 + c*16 + ln;
      float bv = bias[col];
      #pragma unroll
      for (int r = 0; r < 2; r++){
        int mb = m0 + wrow*32 + r*16 + q*4;
        bf16x4 pk;
        #pragma unroll
        for (int i = 0; i < 4; i++) pk[i] = (__bf16)(acc[r][c][i] + bv);
        *(bf16x4*)&VTb[col*NTOK + mb] = pk;
      }
    }
  }
}

// ---------------- NATTEN 3D attention via MFMA ----------------
// One wave = one head x one (tq,hq) query row (16 queries, w=0..15).
// Swapped QK^T: S^T = mfma(K,Q) -> lane&15 = query, regs = 4 k-tokens. That C-layout
// IS the B-operand layout of the K=16 PV MFMA, so P feeds PV with zero shuffles/LDS.
// PV: O^T = mfma(A=VT frag, B=P) -> col = query = lane&15: softmax bookkeeping (m,l)
// applies directly to the accumulator regs. Only 2 shuffles per tile (tile-max).
__global__ __launch_bounds__(256) void attn_kernel(const __bf16* __restrict__ Qb,
                                                   const __bf16* __restrict__ Kb,
                                                   const __bf16* __restrict__ VT,
                                                   __bf16* __restrict__ attn){
  int row = blockIdx.x;                 // 0..127
  int tq = row >> 4, hq = row & 15;
  int g  = (blockIdx.y << 2) + (threadIdx.x >> 6);   // head 0..7
  int lane = threadIdx.x & 63;
  int ln = lane & 15, qt = lane >> 4;

  int qbase = (tq << 8) + (hq << 4);
  int h0 = min(max(hq - 2, 0), 11);
  int tlo = max(tq - 4, 0);

  // Q fragment (B-operand of swapped QK^T): query = ln, dims qt*8..qt*8+7
  bf16x8 qf = *(const bf16x8*)&Qb[(qbase + ln)*D + g*32 + qt*8];

  // static w-window mask for this lane: query q=ln, key w = qt*4+r
  int wstart = min(max(ln - 2, 0), 11);
  float msk[4];
  #pragma unroll
  for (int r = 0; r < 4; r++){
    int wk = qt*4 + r;
    msk[r] = (wk >= wstart && wk <= wstart + 4) ? 0.0f : -INFINITY;
  }

  const float sc = 0.17677669529663687f;   // 1/sqrt(32)
  float m_run = -INFINITY, l_run = 0.0f;
  f32x4 o0 = (f32x4){0,0,0,0}, o1 = (f32x4){0,0,0,0};
  f32x4 zero = (f32x4){0,0,0,0};

  for (int tp = tlo; tp <= tq; tp++){
    #pragma unroll
    for (int hp = 0; hp < 5; hp++){
      int kb0 = (tp << 8) + ((h0 + hp) << 4);
      // K fragment (A-operand): k-token = ln, dims qt*8..qt*8+7
      bf16x8 kf = *(const bf16x8*)&Kb[(kb0 + ln)*D + g*32 + qt*8];
      f32x4 s = __builtin_amdgcn_mfma_f32_16x16x32_bf16(kf, qf, zero, 0, 0, 0);
      // scale + mask; this lane holds 4 k-scores of query ln
      float sv0 = s[0]*sc + msk[0];
      float sv1 = s[1]*sc + msk[1];
      float sv2 = s[2]*sc + msk[2];
      float sv3 = s[3]*sc + msk[3];
      float tm = fmaxf(fmaxf(sv0, sv1), fmaxf(sv2, sv3));
      tm = fmaxf(tm, __shfl_xor(tm, 16, 64));
      tm = fmaxf(tm, __shfl_xor(tm, 32, 64));       // tile max per query
      float mnew = fmaxf(m_run, tm);
      float rs = __expf(m_run - mnew);              // first tile: exp(-inf)=0
      float p0 = __expf(sv0 - mnew), p1 = __expf(sv1 - mnew);
      float p2 = __expf(sv2 - mnew), p3 = __expf(sv3 - mnew);
      bf16x4 pa;
      pa[0] = (__bf16)p0; pa[1] = (__bf16)p1; pa[2] = (__bf16)p2; pa[3] = (__bf16)p3;
      // keep l consistent with the bf16-rounded P actually fed to PV
      l_run = l_run*rs + (float)pa[0] + (float)pa[1] + (float)pa[2] + (float)pa[3];
      #pragma unroll
      for (int i = 0; i < 4; i++){ o0[i] *= rs; o1[i] *= rs; }
      m_run = mnew;
      // V^T fragments (A-operand): dim = ln (within 16-block), k-token = qt*4+j
      bf16x4 v0 = *(const bf16x4*)&VT[(g*32      + ln)*NTOK + kb0 + qt*4];
      bf16x4 v1 = *(const bf16x4*)&VT[(g*32 + 16 + ln)*NTOK + kb0 + qt*4];
      o0 = mfma16x16x16bf16(v0, pa, o0);
      o1 = mfma16x16x16bf16(v1, pa, o1);
    }
  }
  // combine l across the 4 lane-groups (each covered a disjoint k subset)
  l_run += __shfl_xor(l_run, 16, 64);
  l_run += __shfl_xor(l_run, 32, 64);
  float linv = 1.0f / l_run;
  // O^T layout: col = query = ln, row = dim = qt*4+r -> 4 consecutive dims, 8B packed store
  int obase = (qbase + ln)*D + g*32;
  bf16x4 s0, s1;
  #pragma unroll
  for (int r = 0; r < 4; r++){
    s0[r] = (__bf16)(o0[r] * linv);
    s1[r] = (__bf16)(o1[r] * linv);
  }
  *(bf16x4*)&attn[obase      + qt*4] = s0;
  *(bf16x4*)&attn[obase + 16 + qt*4] = s1;
}

// ---------------- o-proj + bias + residual(X fp32) -> h fp32 ----------------
__global__ __launch_bounds__(256) void oproj_kernel(const __bf16* __restrict__ A,
                                                    const __bf16* __restrict__ WoT,
                                                    const float* __restrict__ VEC,
                                                    const float* __restrict__ X,
                                                    float* __restrict__ h){
  __shared__ __align__(16) __bf16 As[64][72];
  __shared__ __align__(16) __bf16 Bs[64][72];
  int m0 = blockIdx.x*64, n0 = blockIdx.y*64;
  GEMM_PROLOGUE
  gemm_core(A, WoT, D, m0, n0, As, Bs, acc);
  #pragma unroll
  for (int c = 0; c < 2; c++){
    int col = n0 + wcol*32 + c*16 + ln;
    float bv = VEC[1280 + col];
    #pragma unroll
    for (int r = 0; r < 2; r++){
      #pragma unroll
      for (int i = 0; i < 4; i++){
        int m = m0 + wrow*32 + r*16 + q*4 + i;
        int idx = m*D + col;
        h[idx] = acc[r][c][i] + bv + X[idx];
      }
    }
  }
}

// ---------------- FFN up: ffh = silu(y@w1) * (y@w2), bf16 out ----------------
__global__ __launch_bounds__(256) void ffn1_kernel(const __bf16* __restrict__ y,
                                                   const __bf16* __restrict__ W1T,
                                                   const __bf16* __restrict__ W2T,
                                                   __bf16* __restrict__ ffh){
  __shared__ __align__(16) __bf16 As [64][72];
  __shared__ __align__(16) __bf16 B1s[64][72];
  __shared__ __align__(16) __bf16 B2s[64][72];
  int m0 = blockIdx.x*64, n0 = blockIdx.y*64;
  int tid = threadIdx.x;
  int wave = tid >> 6, lane = tid & 63;
  int wrow = wave & 1, wcol = wave >> 1;
  int q = lane >> 4, ln = lane & 15;
  f32x4 acc1[2][2], acc2[2][2];
  #pragma unroll
  for (int r = 0; r < 2; r++)
    #pragma unroll
    for (int c = 0; c < 2; c++){ acc1[r][c] = (f32x4){0,0,0,0}; acc2[r][c] = (f32x4){0,0,0,0}; }

  for (int k0 = 0; k0 < D; k0 += 64){
    #pragma unroll
    for (int j = 0; j < 2; j++){
      int c = j*256 + tid;
      int row = c >> 3, seg = c & 7;
      *(float4*)&As [row][seg*8] = *(const float4*)&y  [(m0+row)*D + k0 + seg*8];
      *(float4*)&B1s[row][seg*8] = *(const float4*)&W1T[(n0+row)*D + k0 + seg*8];
      *(float4*)&B2s[row][seg*8] = *(const float4*)&W2T[(n0+row)*D + k0 + seg*8];
    }
    __syncthreads();
    #pragma unroll
    for (int ks = 0; ks < 2; ks++){
      bf16x8 a0 = *(const bf16x8*)&As [wrow*32      + ln][ks*32 + q*8];
      bf16x8 a1 = *(const bf16x8*)&As [wrow*32 + 16 + ln][ks*32 + q*8];
      bf16x8 p0 = *(const bf16x8*)&B1s[wcol*32      + ln][ks*32 + q*8];
      bf16x8 p1 = *(const bf16x8*)&B1s[wcol*32 + 16 + ln][ks*32 + q*8];
      bf16x8 u0 = *(const bf16x8*)&B2s[wcol*32      + ln][ks*32 + q*8];
      bf16x8 u1 = *(const bf16x8*)&B2s[wcol*32 + 16 + ln][ks*32 + q*8];
      acc1[0][0] = __builtin_amdgcn_mfma_f32_16x16x32_bf16(a0, p0, acc1[0][0], 0,0,0);
      acc1[0][1] = __builtin_amdgcn_mfma_f32_16x16x32_bf16(a0, p1, acc1[0][1], 0,0,0);
      acc1[1][0] = __builtin_amdgcn_mfma_f32_16x16x32_bf16(a1, p0, acc1[1][0], 0,0,0);
      acc1[1][1] = __builtin_amdgcn_mfma_f32_16x16x32_bf16(a1, p1, acc1[1][1], 0,0,0);
      acc2[0][0] = __builtin_amdgcn_mfma_f32_16x16x32_bf16(a0, u0, acc2[0][0], 0,0,0);
      acc2[0][1] = __builtin_amdgcn_mfma_f32_16x16x32_bf16(a0, u1, acc2[0][1], 0,0,0);
      acc2[1][0] = __builtin_amdgcn_mfma_f32_16x16x32_bf16(a1, u0, acc2[1][0], 0,0,0);
      acc2[1][1] = __builtin_amdgcn_mfma_f32_16x16x32_bf16(a1, u1, acc2[1][1], 0,0,0);
    }
    __syncthreads();
  }
  #pragma unroll
  for (int c = 0; c < 2; c++){
    int col = n0 + wcol*32 + c*16 + ln;
    #pragma unroll
    for (int r = 0; r < 2; r++){
      #pragma unroll
      for (int i = 0; i < 4; i++){
        int m = m0 + wrow*32 + r*16 + q*4 + i;
        float gv = acc1[r][c][i], u = acc2[r][c][i];
        float sig = 1.0f / (1.0f + __expf(-gv));
        ffh[m*FF + col] = (__bf16)(gv * sig * u);
      }
    }
  }
}

// ---------------- FFN down + residual + final store (dtype-branching) ----------------
__global__ __launch_bounds__(256) void ffn2_kernel(const __bf16* __restrict__ ffh,
                                                   const __bf16* __restrict__ W3T,
                                                   const float* __restrict__ h,
                                                   const unsigned int* __restrict__ tagp,
                                                   void* __restrict__ outp){
  __shared__ __align__(16) __bf16 As[64][72];
  __shared__ __align__(16) __bf16 Bs[64][72];
  int m0 = blockIdx.x*64, n0 = blockIdx.y*64;
  GEMM_PROLOGUE
  gemm_core(ffh, W3T, FF, m0, n0, As, Bs, acc);
  bool isf32 = (*tagp == 0x3F800000u);
  #pragma unroll
  for (int c = 0; c < 2; c++){
    int col = n0 + wcol*32 + c*16 + ln;
    #pragma unroll
    for (int r = 0; r < 2; r++){
      #pragma unroll
      for (int i = 0; i < 4; i++){
        int m = m0 + wrow*32 + r*16 + q*4 + i;
        int idx = m*D + col;
        float val = acc[r][c][i] + h[idx];
        if (isf32) ((float*)outp)[idx] = val;
        else       ((__bf16*)outp)[idx] = (__bf16)val;
      }
    }
  }
}

// ---------------- launcher ----------------
extern "C" void kernel_launch(void* const* d_in, const int* in_sizes, int n_in,
                              void* d_out, int out_size, void* d_ws, size_t ws_size,
                              hipStream_t stream){
  char* ws = (char*)d_ws;
  float*  X    = (float*)(ws);                       // 2 MB
  float*  VEC  = (float*)(ws + 2097152);             // 6 KB (pad to 8 KB)
  __bf16* WT   = (__bf16*)(ws + 2097152 + 8192);     // 2 MB
  __bf16* XN   = (__bf16*)(ws + 4202496);            // 1 MB
  __bf16* Qb   = (__bf16*)(ws + 5251072);            // 1 MB
  __bf16* Kb   = Qb + NTOK*D;                        // 1 MB
  __bf16* VTb  = Kb + NTOK*D;                        // 1 MB (transposed V)
  __bf16* ATT  = (__bf16*)(ws + 11542528);           // 1 MB
  float*  Hb   = (float*)(ws + 12591104);            // 2 MB
  __bf16* Yb   = (__bf16*)(ws + 14688256);           // 1 MB
  __bf16* FFH  = (__bf16*)Qb;                        // reuse q/k/vt region (4 MB avail) after attention

  const unsigned int* tagp = (const unsigned int*)d_in[1];

  MiscArgs ma;
  ma.x = d_in[0];
  ma.vec[0] = d_in[1]; ma.vec[1] = d_in[2]; ma.vec[2] = d_in[4];
  ma.vec[3] = d_in[6]; ma.vec[4] = d_in[8]; ma.vec[5] = d_in[10];

  TPArgs ta;
  ta.src[0] = d_in[3];  ta.src[1] = d_in[5];  ta.src[2] = d_in[7];
  ta.src[3] = d_in[9];  ta.src[4] = d_in[11]; ta.src[5] = d_in[12];
  ta.src[6] = d_in[13];

  stage_misc_kernel<<<2054, 256, 0, stream>>>(ma, X, VEC, tagp);
  transpose_w_kernel<<<4096, 256, 0, stream>>>(ta, WT, tagp);
  rmsnorm_kernel<<<NTOK, 256, 0, stream>>>(X, VEC, XN);
  qkv_kernel<<<dim3(NTOK/64, 12), 256, 0, stream>>>(XN, WT, VEC, Qb, Kb, VTb);
  attn_kernel<<<dim3(128, 2), 256, 0, stream>>>(Qb, Kb, VTb, ATT);
  oproj_kernel<<<dim3(NTOK/64, 4), 256, 0, stream>>>(ATT, WT + 196608, VEC, X, Hb);
  rmsnorm_kernel<<<NTOK, 256, 0, stream>>>(Hb, VEC + 256, Yb);
  ffn1_kernel<<<dim3(NTOK/64, 16), 256, 0, stream>>>(Yb, WT + 262144, WT + 524288, FFH);
  ffn2_kernel<<<dim3(NTOK/64, 4), 256, 0, stream>>>(FFH, WT + 786432, Hb, tagp, d_out);
}

// Round 3
// 158.320 us; speedup vs baseline: 1.2966x; 1.0465x over previous
//
#include <hip/hip_runtime.h>
#include <hip/hip_bf16.h>

typedef __attribute__((ext_vector_type(8))) __bf16 bf16x8;
typedef __attribute__((ext_vector_type(4))) __bf16 bf16x4;
typedef __attribute__((ext_vector_type(4))) short shortx4;
typedef __attribute__((ext_vector_type(4))) float f32x4;

#define D    256
#define FF   1024
#define NTOK 2048   // 8*16*16

__device__ __forceinline__ float ldf(const void* p, int i, bool isf32){
  return isf32 ? ((const float*)p)[i] : (float)(((const __bf16*)p)[i]);
}

// K=16 bf16 MFMA wrapper (builtin name differs across ROCm versions)
__device__ __forceinline__ f32x4 mfma16x16x16bf16(bf16x4 a, bf16x4 b, f32x4 c){
#if __has_builtin(__builtin_amdgcn_mfma_f32_16x16x16_bf16)
  return __builtin_amdgcn_mfma_f32_16x16x16_bf16(a, b, c, 0, 0, 0);
#elif __has_builtin(__builtin_amdgcn_mfma_f32_16x16x16bf16_1k)
  return __builtin_amdgcn_mfma_f32_16x16x16bf16_1k(__builtin_bit_cast(shortx4, a),
                                                   __builtin_bit_cast(shortx4, b), c, 0, 0, 0);
#else
  asm volatile("v_mfma_f32_16x16x16_bf16 %0, %1, %2, %0" : "+v"(c) : "v"(a), "v"(b));
  return c;
#endif
}

struct MiscArgs { const void* x; const void* vec[6]; };
struct TPArgs { const void* src[7]; };

// ---------------- fused prep: weight transpose (LDS-tiled) + x-copy + rmsnorm1 + VEC ----------------
// blocks 0..1023   : 32x32 transpose tiles, coalesced read AND write via LDS [32][33]
// blocks 1024..3071: one token each — copy x row to X (f32) and write rmsnorm'd bf16 row to XN
// block  3072      : stage the 6 norm/bias vectors into VEC
__global__ __launch_bounds__(256) void prep_kernel(MiscArgs a, TPArgs ta,
                                                   float* __restrict__ X,
                                                   float* __restrict__ VEC,
                                                   __bf16* __restrict__ WT,
                                                   __bf16* __restrict__ XN,
                                                   const unsigned int* __restrict__ tagp){
  __shared__ float tl[32][33];
  __shared__ float red[4];
  bool isf32 = (*tagp == 0x3F800000u);
  int b = blockIdx.x, tid = threadIdx.x;

  if (b < 1024){
    // ---- weight transpose tile ----
    const void* src; int Kd, Nd, dstOff, tk, tn;
    if (b < 256){
      int mat = b >> 6, t = b & 63;
      src = ta.src[mat]; Kd = 256; Nd = 256; dstOff = mat*65536;
      tk = t >> 3; tn = t & 7;
    } else if (b < 768){
      int mat = (b - 256) >> 8, t = (b - 256) & 255;
      src = ta.src[4 + mat]; Kd = 256; Nd = 1024; dstOff = 262144 + mat*262144;
      tk = t >> 5; tn = t & 31;
    } else {
      int t = b - 768;
      src = ta.src[6]; Kd = 1024; Nd = 256; dstOff = 786432;
      tk = t >> 3; tn = t & 7;
    }
    int tx = tid & 31, ty = tid >> 5;
    int k0 = tk*32, n0 = tn*32;
    #pragma unroll
    for (int i = 0; i < 4; i++){
      int kk = ty + i*8;
      tl[kk][tx] = ldf(src, (k0 + kk)*Nd + n0 + tx, isf32);   // coalesced in n
    }
    __syncthreads();
    #pragma unroll
    for (int i = 0; i < 4; i++){
      int nn = ty + i*8;
      WT[dstOff + (n0 + nn)*Kd + k0 + tx] = (__bf16)tl[tx][nn];  // coalesced in k
    }
  } else if (b < 3072){
    // ---- token copy + rmsnorm ----
    int tok = b - 1024;
    int idx = tok*D + tid;
    float xv = ldf(a.x, idx, isf32);
    X[idx] = xv;
    float s = xv*xv;
    #pragma unroll
    for (int d = 32; d > 0; d >>= 1) s += __shfl_xor(s, d, 64);
    if ((tid & 63) == 0) red[tid >> 6] = s;
    __syncthreads();
    float tot = red[0]+red[1]+red[2]+red[3];
    float w = ldf(a.vec[0], tid, isf32);   // norm1_w straight from input (no VEC dep)
    XN[idx] = (__bf16)(xv * rsqrtf(tot*(1.0f/D) + 1e-6f) * w);
  } else {
    // ---- VEC staging ----
    for (int i = tid; i < 1536; i += 256)
      VEC[i] = ldf(a.vec[i >> 8], i & 255, isf32);
  }
}

// ---------------- rmsnorm: one block per token, bf16 out ----------------
__global__ __launch_bounds__(256) void rmsnorm_kernel(const float* __restrict__ x,
                                                      const float* __restrict__ w,
                                                      __bf16* __restrict__ out){
  int tok = blockIdx.x, tid = threadIdx.x;
  int idx = tok*D + tid;
  float xv = x[idx];
  float s = xv*xv;
  #pragma unroll
  for (int d = 32; d > 0; d >>= 1) s += __shfl_xor(s, d, 64);
  __shared__ float red[4];
  if ((tid & 63) == 0) red[tid >> 6] = s;
  __syncthreads();
  float tot = red[0]+red[1]+red[2]+red[3];
  out[idx] = (__bf16)(xv * rsqrtf(tot*(1.0f/D) + 1e-6f) * w[tid]);
}

// ---------------- MFMA GEMM core: 64x64 tile, BK=64, A[M][K] bf16, B[N][K] bf16 ----------------
typedef __bf16 ldsrow[72];   // +8 pad

__device__ __forceinline__ void gemm_core(const __bf16* __restrict__ A,
                                          const __bf16* __restrict__ B,
                                          int K, int m0, int n0,
                                          ldsrow* As, ldsrow* Bs,
                                          f32x4 acc[2][2]){
  int tid = threadIdx.x;
  int wave = tid >> 6, lane = tid & 63;
  int wrow = wave & 1, wcol = wave >> 1;
  int q = lane >> 4, ln = lane & 15;
  for (int k0 = 0; k0 < K; k0 += 64){
    #pragma unroll
    for (int j = 0; j < 2; j++){
      int c = j*256 + tid;
      int row = c >> 3, seg = c & 7;
      *(float4*)&As[row][seg*8] = *(const float4*)&A[(m0+row)*K + k0 + seg*8];
      *(float4*)&Bs[row][seg*8] = *(const float4*)&B[(n0+row)*K + k0 + seg*8];
    }
    __syncthreads();
    #pragma unroll
    for (int ks = 0; ks < 2; ks++){
      bf16x8 a0 = *(const bf16x8*)&As[wrow*32      + ln][ks*32 + q*8];
      bf16x8 a1 = *(const bf16x8*)&As[wrow*32 + 16 + ln][ks*32 + q*8];
      bf16x8 b0 = *(const bf16x8*)&Bs[wcol*32      + ln][ks*32 + q*8];
      bf16x8 b1 = *(const bf16x8*)&Bs[wcol*32 + 16 + ln][ks*32 + q*8];
      acc[0][0] = __builtin_amdgcn_mfma_f32_16x16x32_bf16(a0, b0, acc[0][0], 0, 0, 0);
      acc[0][1] = __builtin_amdgcn_mfma_f32_16x16x32_bf16(a0, b1, acc[0][1], 0, 0, 0);
      acc[1][0] = __builtin_amdgcn_mfma_f32_16x16x32_bf16(a1, b0, acc[1][0], 0, 0, 0);
      acc[1][1] = __builtin_amdgcn_mfma_f32_16x16x32_bf16(a1, b1, acc[1][1], 0, 0, 0);
    }
    __syncthreads();
  }
}

#define GEMM_PROLOGUE \
  int tid = threadIdx.x; \
  int wave = tid >> 6, lane = tid & 63; \
  int wrow = wave & 1, wcol = wave >> 1; \
  int q = lane >> 4, ln = lane & 15; \
  (void)tid; \
  f32x4 acc[2][2]; \
  acc[0][0] = (f32x4){0,0,0,0}; acc[0][1] = (f32x4){0,0,0,0}; \
  acc[1][0] = (f32x4){0,0,0,0}; acc[1][1] = (f32x4){0,0,0,0};

// ---------------- fused QKV: virtual N = 768, bf16 out (+bias) ----------------
__global__ __launch_bounds__(256) void qkv_kernel(const __bf16* __restrict__ xn,
                                                  const __bf16* __restrict__ WT,
                                                  const float* __restrict__ VEC,
                                                  __bf16* __restrict__ Qb,
                                                  __bf16* __restrict__ Kb,
                                                  __bf16* __restrict__ VTb){
  __shared__ __align__(16) __bf16 As[64][72];
  __shared__ __align__(16) __bf16 Bs[64][72];
  int m0 = blockIdx.x*64;
  int sel = blockIdx.y >> 2, n0 = (blockIdx.y & 3)*64;
  const __bf16* B = WT + sel*65536;
  const float* bias = VEC + 512 + sel*256;
  GEMM_PROLOGUE
  gemm_core(xn, B, D, m0, n0, As, Bs, acc);
  if (sel < 2){
    __bf16* O = (sel == 0) ? Qb : Kb;
    #pragma unroll
    for (int c = 0; c < 2; c++){
      int col = n0 + wcol*32 + c*16 + ln;
      float bv = bias[col];
      #pragma unroll
      for (int r = 0; r < 2; r++){
        #pragma unroll
        for (int i = 0; i < 4; i++){
          int m = m0 + wrow*32 + r*16 + q*4 + i;
          O[m*D + col] = (__bf16)(acc[r][c][i] + bv);
        }
      }
    }
  } else {
    #pragma unroll
    for (int c = 0; c < 2; c++){
      int col = n0 + wcol*32 + c*16 + ln;
      float bv = bias[col];
      #pragma unroll
      for (int r = 0; r < 2; r++){
        int mb = m0 + wrow*32 + r*16 + q*4;
        bf16x4 pk;
        #pragma unroll
        for (int i = 0; i < 4; i++) pk[i] = (__bf16)(acc[r][c][i] + bv);
        *(bf16x4*)&VTb[col*NTOK + mb] = pk;
      }
    }
  }
}

// ---------------- NATTEN 3D attention via MFMA (swapped QK^T; PV via K=16 MFMA) ----------------
__global__ __launch_bounds__(256) void attn_kernel(const __bf16* __restrict__ Qb,
                                                   const __bf16* __restrict__ Kb,
                                                   const __bf16* __restrict__ VT,
                                                   __bf16* __restrict__ attn){
  int row = blockIdx.x;                 // 0..127
  int tq = row >> 4, hq = row & 15;
  int g  = (blockIdx.y << 2) + (threadIdx.x >> 6);   // head 0..7
  int lane = threadIdx.x & 63;
  int ln = lane & 15, qt = lane >> 4;

  int qbase = (tq << 8) + (hq << 4);
  int h0 = min(max(hq - 2, 0), 11);
  int tlo = max(tq - 4, 0);

  bf16x8 qf = *(const bf16x8*)&Qb[(qbase + ln)*D + g*32 + qt*8];

  int wstart = min(max(ln - 2, 0), 11);
  float msk[4];
  #pragma unroll
  for (int r = 0; r < 4; r++){
    int wk = qt*4 + r;
    msk[r] = (wk >= wstart && wk <= wstart + 4) ? 0.0f : -INFINITY;
  }

  const float sc = 0.17677669529663687f;   // 1/sqrt(32)
  float m_run = -INFINITY, l_run = 0.0f;
  f32x4 o0 = (f32x4){0,0,0,0}, o1 = (f32x4){0,0,0,0};
  f32x4 zero = (f32x4){0,0,0,0};

  for (int tp = tlo; tp <= tq; tp++){
    #pragma unroll
    for (int hp = 0; hp < 5; hp++){
      int kb0 = (tp << 8) + ((h0 + hp) << 4);
      bf16x8 kf = *(const bf16x8*)&Kb[(kb0 + ln)*D + g*32 + qt*8];
      f32x4 s = __builtin_amdgcn_mfma_f32_16x16x32_bf16(kf, qf, zero, 0, 0, 0);
      float sv0 = s[0]*sc + msk[0];
      float sv1 = s[1]*sc + msk[1];
      float sv2 = s[2]*sc + msk[2];
      float sv3 = s[3]*sc + msk[3];
      float tm = fmaxf(fmaxf(sv0, sv1), fmaxf(sv2, sv3));
      tm = fmaxf(tm, __shfl_xor(tm, 16, 64));
      tm = fmaxf(tm, __shfl_xor(tm, 32, 64));
      float mnew = fmaxf(m_run, tm);
      float rs = __expf(m_run - mnew);
      float p0 = __expf(sv0 - mnew), p1 = __expf(sv1 - mnew);
      float p2 = __expf(sv2 - mnew), p3 = __expf(sv3 - mnew);
      bf16x4 pa;
      pa[0] = (__bf16)p0; pa[1] = (__bf16)p1; pa[2] = (__bf16)p2; pa[3] = (__bf16)p3;
      l_run = l_run*rs + (float)pa[0] + (float)pa[1] + (float)pa[2] + (float)pa[3];
      #pragma unroll
      for (int i = 0; i < 4; i++){ o0[i] *= rs; o1[i] *= rs; }
      m_run = mnew;
      bf16x4 v0 = *(const bf16x4*)&VT[(g*32      + ln)*NTOK + kb0 + qt*4];
      bf16x4 v1 = *(const bf16x4*)&VT[(g*32 + 16 + ln)*NTOK + kb0 + qt*4];
      o0 = mfma16x16x16bf16(v0, pa, o0);
      o1 = mfma16x16x16bf16(v1, pa, o1);
    }
  }
  l_run += __shfl_xor(l_run, 16, 64);
  l_run += __shfl_xor(l_run, 32, 64);
  float linv = 1.0f / l_run;
  int obase = (qbase + ln)*D + g*32;
  bf16x4 s0, s1;
  #pragma unroll
  for (int r = 0; r < 4; r++){
    s0[r] = (__bf16)(o0[r] * linv);
    s1[r] = (__bf16)(o1[r] * linv);
  }
  *(bf16x4*)&attn[obase      + qt*4] = s0;
  *(bf16x4*)&attn[obase + 16 + qt*4] = s1;
}

// ---------------- o-proj + bias + residual(X fp32) -> h fp32 ----------------
__global__ __launch_bounds__(256) void oproj_kernel(const __bf16* __restrict__ A,
                                                    const __bf16* __restrict__ WoT,
                                                    const float* __restrict__ VEC,
                                                    const float* __restrict__ X,
                                                    float* __restrict__ h){
  __shared__ __align__(16) __bf16 As[64][72];
  __shared__ __align__(16) __bf16 Bs[64][72];
  int m0 = blockIdx.x*64, n0 = blockIdx.y*64;
  GEMM_PROLOGUE
  gemm_core(A, WoT, D, m0, n0, As, Bs, acc);
  #pragma unroll
  for (int c = 0; c < 2; c++){
    int col = n0 + wcol*32 + c*16 + ln;
    float bv = VEC[1280 + col];
    #pragma unroll
    for (int r = 0; r < 2; r++){
      #pragma unroll
      for (int i = 0; i < 4; i++){
        int m = m0 + wrow*32 + r*16 + q*4 + i;
        int idx = m*D + col;
        h[idx] = acc[r][c][i] + bv + X[idx];
      }
    }
  }
}

// ---------------- FFN up: ffh = silu(y@w1) * (y@w2), bf16 out ----------------
__global__ __launch_bounds__(256) void ffn1_kernel(const __bf16* __restrict__ y,
                                                   const __bf16* __restrict__ W1T,
                                                   const __bf16* __restrict__ W2T,
                                                   __bf16* __restrict__ ffh){
  __shared__ __align__(16) __bf16 As [64][72];
  __shared__ __align__(16) __bf16 B1s[64][72];
  __shared__ __align__(16) __bf16 B2s[64][72];
  int m0 = blockIdx.x*64, n0 = blockIdx.y*64;
  int tid = threadIdx.x;
  int wave = tid >> 6, lane = tid & 63;
  int wrow = wave & 1, wcol = wave >> 1;
  int q = lane >> 4, ln = lane & 15;
  f32x4 acc1[2][2], acc2[2][2];
  #pragma unroll
  for (int r = 0; r < 2; r++)
    #pragma unroll
    for (int c = 0; c < 2; c++){ acc1[r][c] = (f32x4){0,0,0,0}; acc2[r][c] = (f32x4){0,0,0,0}; }

  for (int k0 = 0; k0 < D; k0 += 64){
    #pragma unroll
    for (int j = 0; j < 2; j++){
      int c = j*256 + tid;
      int row = c >> 3, seg = c & 7;
      *(float4*)&As [row][seg*8] = *(const float4*)&y  [(m0+row)*D + k0 + seg*8];
      *(float4*)&B1s[row][seg*8] = *(const float4*)&W1T[(n0+row)*D + k0 + seg*8];
      *(float4*)&B2s[row][seg*8] = *(const float4*)&W2T[(n0+row)*D + k0 + seg*8];
    }
    __syncthreads();
    #pragma unroll
    for (int ks = 0; ks < 2; ks++){
      bf16x8 a0 = *(const bf16x8*)&As [wrow*32      + ln][ks*32 + q*8];
      bf16x8 a1 = *(const bf16x8*)&As [wrow*32 + 16 + ln][ks*32 + q*8];
      bf16x8 p0 = *(const bf16x8*)&B1s[wcol*32      + ln][ks*32 + q*8];
      bf16x8 p1 = *(const bf16x8*)&B1s[wcol*32 + 16 + ln][ks*32 + q*8];
      bf16x8 u0 = *(const bf16x8*)&B2s[wcol*32      + ln][ks*32 + q*8];
      bf16x8 u1 = *(const bf16x8*)&B2s[wcol*32 + 16 + ln][ks*32 + q*8];
      acc1[0][0] = __builtin_amdgcn_mfma_f32_16x16x32_bf16(a0, p0, acc1[0][0], 0,0,0);
      acc1[0][1] = __builtin_amdgcn_mfma_f32_16x16x32_bf16(a0, p1, acc1[0][1], 0,0,0);
      acc1[1][0] = __builtin_amdgcn_mfma_f32_16x16x32_bf16(a1, p0, acc1[1][0], 0,0,0);
      acc1[1][1] = __builtin_amdgcn_mfma_f32_16x16x32_bf16(a1, p1, acc1[1][1], 0,0,0);
      acc2[0][0] = __builtin_amdgcn_mfma_f32_16x16x32_bf16(a0, u0, acc2[0][0], 0,0,0);
      acc2[0][1] = __builtin_amdgcn_mfma_f32_16x16x32_bf16(a0, u1, acc2[0][1], 0,0,0);
      acc2[1][0] = __builtin_amdgcn_mfma_f32_16x16x32_bf16(a1, u0, acc2[1][0], 0,0,0);
      acc2[1][1] = __builtin_amdgcn_mfma_f32_16x16x32_bf16(a1, u1, acc2[1][1], 0,0,0);
    }
    __syncthreads();
  }
  #pragma unroll
  for (int c = 0; c < 2; c++){
    int col = n0 + wcol*32 + c*16 + ln;
    #pragma unroll
    for (int r = 0; r < 2; r++){
      #pragma unroll
      for (int i = 0; i < 4; i++){
        int m = m0 + wrow*32 + r*16 + q*4 + i;
        float gv = acc1[r][c][i], u = acc2[r][c][i];
        float sig = 1.0f / (1.0f + __expf(-gv));
        ffh[m*FF + col] = (__bf16)(gv * sig * u);
      }
    }
  }
}

// ---------------- FFN down + residual + final store (dtype-branching) ----------------
__global__ __launch_bounds__(256) void ffn2_kernel(const __bf16* __restrict__ ffh,
                                                   const __bf16* __restrict__ W3T,
                                                   const float* __restrict__ h,
                                                   const unsigned int* __restrict__ tagp,
                                                   void* __restrict__ outp){
  __shared__ __align__(16) __bf16 As[64][72];
  __shared__ __align__(16) __bf16 Bs[64][72];
  int m0 = blockIdx.x*64, n0 = blockIdx.y*64;
  GEMM_PROLOGUE
  gemm_core(ffh, W3T, FF, m0, n0, As, Bs, acc);
  bool isf32 = (*tagp == 0x3F800000u);
  #pragma unroll
  for (int c = 0; c < 2; c++){
    int col = n0 + wcol*32 + c*16 + ln;
    #pragma unroll
    for (int r = 0; r < 2; r++){
      #pragma unroll
      for (int i = 0; i < 4; i++){
        int m = m0 + wrow*32 + r*16 + q*4 + i;
        int idx = m*D + col;
        float val = acc[r][c][i] + h[idx];
        if (isf32) ((float*)outp)[idx] = val;
        else       ((__bf16*)outp)[idx] = (__bf16)val;
      }
    }
  }
}

// ---------------- launcher ----------------
extern "C" void kernel_launch(void* const* d_in, const int* in_sizes, int n_in,
                              void* d_out, int out_size, void* d_ws, size_t ws_size,
                              hipStream_t stream){
  char* ws = (char*)d_ws;
  float*  X    = (float*)(ws);                       // 2 MB
  float*  VEC  = (float*)(ws + 2097152);             // 6 KB (pad to 8 KB)
  __bf16* WT   = (__bf16*)(ws + 2097152 + 8192);     // 2 MB
  __bf16* XN   = (__bf16*)(ws + 4202496);            // 1 MB
  __bf16* Qb   = (__bf16*)(ws + 5251072);            // 1 MB
  __bf16* Kb   = Qb + NTOK*D;                        // 1 MB
  __bf16* VTb  = Kb + NTOK*D;                        // 1 MB (transposed V)
  __bf16* ATT  = (__bf16*)(ws + 11542528);           // 1 MB
  float*  Hb   = (float*)(ws + 12591104);            // 2 MB
  __bf16* Yb   = (__bf16*)(ws + 14688256);           // 1 MB
  __bf16* FFH  = (__bf16*)Qb;                        // reuse q/k/vt region after attention

  const unsigned int* tagp = (const unsigned int*)d_in[1];

  MiscArgs ma;
  ma.x = d_in[0];
  ma.vec[0] = d_in[1]; ma.vec[1] = d_in[2]; ma.vec[2] = d_in[4];
  ma.vec[3] = d_in[6]; ma.vec[4] = d_in[8]; ma.vec[5] = d_in[10];

  TPArgs ta;
  ta.src[0] = d_in[3];  ta.src[1] = d_in[5];  ta.src[2] = d_in[7];
  ta.src[3] = d_in[9];  ta.src[4] = d_in[11]; ta.src[5] = d_in[12];
  ta.src[6] = d_in[13];

  prep_kernel<<<3073, 256, 0, stream>>>(ma, ta, X, VEC, WT, XN, tagp);
  qkv_kernel<<<dim3(NTOK/64, 12), 256, 0, stream>>>(XN, WT, VEC, Qb, Kb, VTb);
  attn_kernel<<<dim3(128, 2), 256, 0, stream>>>(Qb, Kb, VTb, ATT);
  oproj_kernel<<<dim3(NTOK/64, 4), 256, 0, stream>>>(ATT, WT + 196608, VEC, X, Hb);
  rmsnorm_kernel<<<NTOK, 256, 0, stream>>>(Hb, VEC + 256, Yb);
  ffn1_kernel<<<dim3(NTOK/64, 16), 256, 0, stream>>>(Yb, WT + 262144, WT + 524288, FFH);
  ffn2_kernel<<<dim3(NTOK/64, 4), 256, 0, stream>>>(FFH, WT + 786432, Hb, tagp, d_out);
}

// Round 4
// 135.069 us; speedup vs baseline: 1.5198x; 1.1721x over previous
//
#include <hip/hip_runtime.h>
#include <hip/hip_bf16.h>

typedef __attribute__((ext_vector_type(8))) __bf16 bf16x8;
typedef __attribute__((ext_vector_type(4))) __bf16 bf16x4;
typedef __attribute__((ext_vector_type(4))) short shortx4;
typedef __attribute__((ext_vector_type(4))) float f32x4;

#define D    256
#define FF   1024
#define NTOK 2048   // 8*16*16

__device__ __forceinline__ float ldf(const void* p, int i, bool isf32){
  return isf32 ? ((const float*)p)[i] : (float)(((const __bf16*)p)[i]);
}

// K=16 bf16 MFMA wrapper (builtin name differs across ROCm versions)
__device__ __forceinline__ f32x4 mfma16x16x16bf16(bf16x4 a, bf16x4 b, f32x4 c){
#if __has_builtin(__builtin_amdgcn_mfma_f32_16x16x16_bf16)
  return __builtin_amdgcn_mfma_f32_16x16x16_bf16(a, b, c, 0, 0, 0);
#elif __has_builtin(__builtin_amdgcn_mfma_f32_16x16x16bf16_1k)
  return __builtin_amdgcn_mfma_f32_16x16x16bf16_1k(__builtin_bit_cast(shortx4, a),
                                                   __builtin_bit_cast(shortx4, b), c, 0, 0, 0);
#else
  asm volatile("v_mfma_f32_16x16x16_bf16 %0, %1, %2, %0" : "+v"(c) : "v"(a), "v"(b));
  return c;
#endif
}

struct MiscArgs { const void* x; const void* vec[6]; };
struct TPArgs { const void* src[7]; };

// ---------------- fused prep: weight transpose (LDS-tiled) + x-copy + rmsnorm1 + VEC ----------------
__global__ __launch_bounds__(256) void prep_kernel(MiscArgs a, TPArgs ta,
                                                   float* __restrict__ X,
                                                   float* __restrict__ VEC,
                                                   __bf16* __restrict__ WT,
                                                   __bf16* __restrict__ XN,
                                                   const unsigned int* __restrict__ tagp){
  __shared__ float tl[32][33];
  __shared__ float red[4];
  bool isf32 = (*tagp == 0x3F800000u);
  int b = blockIdx.x, tid = threadIdx.x;

  if (b < 1024){
    const void* src; int Kd, Nd, dstOff, tk, tn;
    if (b < 256){
      int mat = b >> 6, t = b & 63;
      src = ta.src[mat]; Kd = 256; Nd = 256; dstOff = mat*65536;
      tk = t >> 3; tn = t & 7;
    } else if (b < 768){
      int mat = (b - 256) >> 8, t = (b - 256) & 255;
      src = ta.src[4 + mat]; Kd = 256; Nd = 1024; dstOff = 262144 + mat*262144;
      tk = t >> 5; tn = t & 31;
    } else {
      int t = b - 768;
      src = ta.src[6]; Kd = 1024; Nd = 256; dstOff = 786432;
      tk = t >> 3; tn = t & 7;
    }
    int tx = tid & 31, ty = tid >> 5;
    int k0 = tk*32, n0 = tn*32;
    #pragma unroll
    for (int i = 0; i < 4; i++){
      int kk = ty + i*8;
      tl[kk][tx] = ldf(src, (k0 + kk)*Nd + n0 + tx, isf32);   // coalesced in n
    }
    __syncthreads();
    #pragma unroll
    for (int i = 0; i < 4; i++){
      int nn = ty + i*8;
      WT[dstOff + (n0 + nn)*Kd + k0 + tx] = (__bf16)tl[tx][nn];  // coalesced in k
    }
  } else if (b < 3072){
    int tok = b - 1024;
    int idx = tok*D + tid;
    float xv = ldf(a.x, idx, isf32);
    X[idx] = xv;
    float s = xv*xv;
    #pragma unroll
    for (int d = 32; d > 0; d >>= 1) s += __shfl_xor(s, d, 64);
    if ((tid & 63) == 0) red[tid >> 6] = s;
    __syncthreads();
    float tot = red[0]+red[1]+red[2]+red[3];
    float w = ldf(a.vec[0], tid, isf32);
    XN[idx] = (__bf16)(xv * rsqrtf(tot*(1.0f/D) + 1e-6f) * w);
  } else {
    for (int i = tid; i < 1536; i += 256)
      VEC[i] = ldf(a.vec[i >> 8], i & 255, isf32);
  }
}

// ---------------- rmsnorm: one block per token, bf16 out ----------------
__global__ __launch_bounds__(256) void rmsnorm_kernel(const float* __restrict__ x,
                                                      const float* __restrict__ w,
                                                      __bf16* __restrict__ out){
  int tok = blockIdx.x, tid = threadIdx.x;
  int idx = tok*D + tid;
  float xv = x[idx];
  float s = xv*xv;
  #pragma unroll
  for (int d = 32; d > 0; d >>= 1) s += __shfl_xor(s, d, 64);
  __shared__ float red[4];
  if ((tid & 63) == 0) red[tid >> 6] = s;
  __syncthreads();
  float tot = red[0]+red[1]+red[2]+red[3];
  out[idx] = (__bf16)(xv * rsqrtf(tot*(1.0f/D) + 1e-6f) * w[tid]);
}

// ======================= full-K GEMM cores =======================
// Tiles are staged as one linear copy (rows contiguous for BK = full 256-slice)
// into XOR-swizzled LDS: lds_byte = row*ROWB + (col ^ ((row&7)<<4)).
// Swizzle applied on ds_write AND ds_read (same involution); global reads stay linear.
// One barrier per staged K-extent instead of 2 per BK=64 step.

// ---- BK=256 (ROWB=512): 64x256 bf16 tile = 32KB, 8 chunks/thread ----
__device__ __forceinline__ void stage256(const __bf16* __restrict__ src, int strideElems,
                                         __bf16* __restrict__ lds){
  int tid = threadIdx.x;
  #pragma unroll
  for (int c = 0; c < 8; c++){
    int s = (c*256 + tid) << 4;        // linear byte slot in tile
    int row = s >> 9, col = s & 511;
    *(float4*)((char*)lds + row*512 + (col ^ ((row & 7) << 4))) =
      *(const float4*)((const char*)src + row*strideElems*2 + col);
  }
}
__device__ __forceinline__ bf16x8 lrd256(const __bf16* __restrict__ lds, int row, int cb){
  return *(const bf16x8*)((const char*)lds + row*512 + (cb ^ ((row & 7) << 4)));
}

// ---- BK=128 (ROWB=256): 64x128 bf16 tile = 16KB, 4 chunks/thread ----
__device__ __forceinline__ void stage128(const __bf16* __restrict__ src, int strideElems,
                                         __bf16* __restrict__ lds){
  int tid = threadIdx.x;
  #pragma unroll
  for (int c = 0; c < 4; c++){
    int s = (c*256 + tid) << 4;
    int row = s >> 8, col = s & 255;
    *(float4*)((char*)lds + row*256 + (col ^ ((row & 7) << 4))) =
      *(const float4*)((const char*)src + row*strideElems*2 + col);
  }
}
__device__ __forceinline__ bf16x8 lrd128(const __bf16* __restrict__ lds, int row, int cb){
  return *(const bf16x8*)((const char*)lds + row*256 + (cb ^ ((row & 7) << 4)));
}

__device__ __forceinline__ void mfma256(const __bf16* __restrict__ As, const __bf16* __restrict__ Bs,
                                        f32x4 acc[2][2], int wrow, int wcol, int q, int ln){
  #pragma unroll
  for (int ks = 0; ks < 8; ks++){
    int cb = ks*64 + q*16;
    bf16x8 a0 = lrd256(As, wrow*32      + ln, cb);
    bf16x8 a1 = lrd256(As, wrow*32 + 16 + ln, cb);
    bf16x8 b0 = lrd256(Bs, wcol*32      + ln, cb);
    bf16x8 b1 = lrd256(Bs, wcol*32 + 16 + ln, cb);
    acc[0][0] = __builtin_amdgcn_mfma_f32_16x16x32_bf16(a0, b0, acc[0][0], 0, 0, 0);
    acc[0][1] = __builtin_amdgcn_mfma_f32_16x16x32_bf16(a0, b1, acc[0][1], 0, 0, 0);
    acc[1][0] = __builtin_amdgcn_mfma_f32_16x16x32_bf16(a1, b0, acc[1][0], 0, 0, 0);
    acc[1][1] = __builtin_amdgcn_mfma_f32_16x16x32_bf16(a1, b1, acc[1][1], 0, 0, 0);
  }
}

#define GEMM_PROLOGUE \
  int tid = threadIdx.x; \
  int wave = tid >> 6, lane = tid & 63; \
  int wrow = wave & 1, wcol = wave >> 1; \
  int q = lane >> 4, ln = lane & 15; \
  (void)tid; \
  f32x4 acc[2][2]; \
  acc[0][0] = (f32x4){0,0,0,0}; acc[0][1] = (f32x4){0,0,0,0}; \
  acc[1][0] = (f32x4){0,0,0,0}; acc[1][1] = (f32x4){0,0,0,0};

// ---------------- fused QKV: virtual N = 768, bf16 out (+bias) ----------------
__global__ __launch_bounds__(256) void qkv_kernel(const __bf16* __restrict__ xn,
                                                  const __bf16* __restrict__ WT,
                                                  const float* __restrict__ VEC,
                                                  __bf16* __restrict__ Qb,
                                                  __bf16* __restrict__ Kb,
                                                  __bf16* __restrict__ VTb){
  __shared__ __align__(16) __bf16 As[64][256];
  __shared__ __align__(16) __bf16 Bs[64][256];
  int m0 = blockIdx.x*64;
  int sel = blockIdx.y >> 2, n0 = (blockIdx.y & 3)*64;
  const __bf16* B = WT + sel*65536;
  const float* bias = VEC + 512 + sel*256;
  GEMM_PROLOGUE
  stage256(xn + m0*D, D, &As[0][0]);
  stage256(B  + n0*D, D, &Bs[0][0]);
  __syncthreads();
  mfma256(&As[0][0], &Bs[0][0], acc, wrow, wcol, q, ln);
  if (sel < 2){
    __bf16* O = (sel == 0) ? Qb : Kb;
    #pragma unroll
    for (int c = 0; c < 2; c++){
      int col = n0 + wcol*32 + c*16 + ln;
      float bv = bias[col];
      #pragma unroll
      for (int r = 0; r < 2; r++){
        #pragma unroll
        for (int i = 0; i < 4; i++){
          int m = m0 + wrow*32 + r*16 + q*4 + i;
          O[m*D + col] = (__bf16)(acc[r][c][i] + bv);
        }
      }
    }
  } else {
    #pragma unroll
    for (int c = 0; c < 2; c++){
      int col = n0 + wcol*32 + c*16 + ln;
      float bv = bias[col];
      #pragma unroll
      for (int r = 0; r < 2; r++){
        int mb = m0 + wrow*32 + r*16 + q*4;
        bf16x4 pk;
        #pragma unroll
        for (int i = 0; i < 4; i++) pk[i] = (__bf16)(acc[r][c][i] + bv);
        *(bf16x4*)&VTb[col*NTOK + mb] = pk;
      }
    }
  }
}

// ---------------- NATTEN 3D attention via MFMA (swapped QK^T; PV via K=16 MFMA) ----------------
__global__ __launch_bounds__(256) void attn_kernel(const __bf16* __restrict__ Qb,
                                                   const __bf16* __restrict__ Kb,
                                                   const __bf16* __restrict__ VT,
                                                   __bf16* __restrict__ attn){
  int row = blockIdx.x;                 // 0..127
  int tq = row >> 4, hq = row & 15;
  int g  = (blockIdx.y << 2) + (threadIdx.x >> 6);   // head 0..7
  int lane = threadIdx.x & 63;
  int ln = lane & 15, qt = lane >> 4;

  int qbase = (tq << 8) + (hq << 4);
  int h0 = min(max(hq - 2, 0), 11);
  int tlo = max(tq - 4, 0);

  bf16x8 qf = *(const bf16x8*)&Qb[(qbase + ln)*D + g*32 + qt*8];

  int wstart = min(max(ln - 2, 0), 11);
  float msk[4];
  #pragma unroll
  for (int r = 0; r < 4; r++){
    int wk = qt*4 + r;
    msk[r] = (wk >= wstart && wk <= wstart + 4) ? 0.0f : -INFINITY;
  }

  const float sc = 0.17677669529663687f;   // 1/sqrt(32)
  float m_run = -INFINITY, l_run = 0.0f;
  f32x4 o0 = (f32x4){0,0,0,0}, o1 = (f32x4){0,0,0,0};
  f32x4 zero = (f32x4){0,0,0,0};

  for (int tp = tlo; tp <= tq; tp++){
    #pragma unroll
    for (int hp = 0; hp < 5; hp++){
      int kb0 = (tp << 8) + ((h0 + hp) << 4);
      bf16x8 kf = *(const bf16x8*)&Kb[(kb0 + ln)*D + g*32 + qt*8];
      f32x4 s = __builtin_amdgcn_mfma_f32_16x16x32_bf16(kf, qf, zero, 0, 0, 0);
      float sv0 = s[0]*sc + msk[0];
      float sv1 = s[1]*sc + msk[1];
      float sv2 = s[2]*sc + msk[2];
      float sv3 = s[3]*sc + msk[3];
      float tm = fmaxf(fmaxf(sv0, sv1), fmaxf(sv2, sv3));
      tm = fmaxf(tm, __shfl_xor(tm, 16, 64));
      tm = fmaxf(tm, __shfl_xor(tm, 32, 64));
      float mnew = fmaxf(m_run, tm);
      float rs = __expf(m_run - mnew);
      float p0 = __expf(sv0 - mnew), p1 = __expf(sv1 - mnew);
      float p2 = __expf(sv2 - mnew), p3 = __expf(sv3 - mnew);
      bf16x4 pa;
      pa[0] = (__bf16)p0; pa[1] = (__bf16)p1; pa[2] = (__bf16)p2; pa[3] = (__bf16)p3;
      l_run = l_run*rs + (float)pa[0] + (float)pa[1] + (float)pa[2] + (float)pa[3];
      #pragma unroll
      for (int i = 0; i < 4; i++){ o0[i] *= rs; o1[i] *= rs; }
      m_run = mnew;
      bf16x4 v0 = *(const bf16x4*)&VT[(g*32      + ln)*NTOK + kb0 + qt*4];
      bf16x4 v1 = *(const bf16x4*)&VT[(g*32 + 16 + ln)*NTOK + kb0 + qt*4];
      o0 = mfma16x16x16bf16(v0, pa, o0);
      o1 = mfma16x16x16bf16(v1, pa, o1);
    }
  }
  l_run += __shfl_xor(l_run, 16, 64);
  l_run += __shfl_xor(l_run, 32, 64);
  float linv = 1.0f / l_run;
  int obase = (qbase + ln)*D + g*32;
  bf16x4 s0, s1;
  #pragma unroll
  for (int r = 0; r < 4; r++){
    s0[r] = (__bf16)(o0[r] * linv);
    s1[r] = (__bf16)(o1[r] * linv);
  }
  *(bf16x4*)&attn[obase      + qt*4] = s0;
  *(bf16x4*)&attn[obase + 16 + qt*4] = s1;
}

// ---------------- o-proj + bias + residual(X fp32) -> h fp32 ----------------
__global__ __launch_bounds__(256) void oproj_kernel(const __bf16* __restrict__ A,
                                                    const __bf16* __restrict__ WoT,
                                                    const float* __restrict__ VEC,
                                                    const float* __restrict__ X,
                                                    float* __restrict__ h){
  __shared__ __align__(16) __bf16 As[64][256];
  __shared__ __align__(16) __bf16 Bs[64][256];
  int m0 = blockIdx.x*64, n0 = blockIdx.y*64;
  GEMM_PROLOGUE
  stage256(A   + m0*D, D, &As[0][0]);
  stage256(WoT + n0*D, D, &Bs[0][0]);
  __syncthreads();
  mfma256(&As[0][0], &Bs[0][0], acc, wrow, wcol, q, ln);
  #pragma unroll
  for (int c = 0; c < 2; c++){
    int col = n0 + wcol*32 + c*16 + ln;
    float bv = VEC[1280 + col];
    #pragma unroll
    for (int r = 0; r < 2; r++){
      #pragma unroll
      for (int i = 0; i < 4; i++){
        int m = m0 + wrow*32 + r*16 + q*4 + i;
        int idx = m*D + col;
        h[idx] = acc[r][c][i] + bv + X[idx];
      }
    }
  }
}

// ---------------- FFN up: ffh = silu(y@w1) * (y@w2), bf16 out (BK=128, 2 iters) ----------------
__global__ __launch_bounds__(256) void ffn1_kernel(const __bf16* __restrict__ y,
                                                   const __bf16* __restrict__ W1T,
                                                   const __bf16* __restrict__ W2T,
                                                   __bf16* __restrict__ ffh){
  __shared__ __align__(16) __bf16 As [64][128];
  __shared__ __align__(16) __bf16 B1s[64][128];
  __shared__ __align__(16) __bf16 B2s[64][128];
  int m0 = blockIdx.x*64, n0 = blockIdx.y*64;
  int tid = threadIdx.x;
  int wave = tid >> 6, lane = tid & 63;
  int wrow = wave & 1, wcol = wave >> 1;
  int q = lane >> 4, ln = lane & 15;
  f32x4 acc1[2][2], acc2[2][2];
  #pragma unroll
  for (int r = 0; r < 2; r++)
    #pragma unroll
    for (int c = 0; c < 2; c++){ acc1[r][c] = (f32x4){0,0,0,0}; acc2[r][c] = (f32x4){0,0,0,0}; }

  #pragma unroll
  for (int k0 = 0; k0 < D; k0 += 128){
    if (k0) __syncthreads();
    stage128(y   + m0*D + k0, D, &As [0][0]);
    stage128(W1T + n0*D + k0, D, &B1s[0][0]);
    stage128(W2T + n0*D + k0, D, &B2s[0][0]);
    __syncthreads();
    #pragma unroll
    for (int ks = 0; ks < 4; ks++){
      int cb = ks*64 + q*16;
      bf16x8 a0 = lrd128(&As [0][0], wrow*32      + ln, cb);
      bf16x8 a1 = lrd128(&As [0][0], wrow*32 + 16 + ln, cb);
      bf16x8 p0 = lrd128(&B1s[0][0], wcol*32      + ln, cb);
      bf16x8 p1 = lrd128(&B1s[0][0], wcol*32 + 16 + ln, cb);
      bf16x8 u0 = lrd128(&B2s[0][0], wcol*32      + ln, cb);
      bf16x8 u1 = lrd128(&B2s[0][0], wcol*32 + 16 + ln, cb);
      acc1[0][0] = __builtin_amdgcn_mfma_f32_16x16x32_bf16(a0, p0, acc1[0][0], 0,0,0);
      acc1[0][1] = __builtin_amdgcn_mfma_f32_16x16x32_bf16(a0, p1, acc1[0][1], 0,0,0);
      acc1[1][0] = __builtin_amdgcn_mfma_f32_16x16x32_bf16(a1, p0, acc1[1][0], 0,0,0);
      acc1[1][1] = __builtin_amdgcn_mfma_f32_16x16x32_bf16(a1, p1, acc1[1][1], 0,0,0);
      acc2[0][0] = __builtin_amdgcn_mfma_f32_16x16x32_bf16(a0, u0, acc2[0][0], 0,0,0);
      acc2[0][1] = __builtin_amdgcn_mfma_f32_16x16x32_bf16(a0, u1, acc2[0][1], 0,0,0);
      acc2[1][0] = __builtin_amdgcn_mfma_f32_16x16x32_bf16(a1, u0, acc2[1][0], 0,0,0);
      acc2[1][1] = __builtin_amdgcn_mfma_f32_16x16x32_bf16(a1, u1, acc2[1][1], 0,0,0);
    }
  }
  #pragma unroll
  for (int c = 0; c < 2; c++){
    int col = n0 + wcol*32 + c*16 + ln;
    #pragma unroll
    for (int r = 0; r < 2; r++){
      #pragma unroll
      for (int i = 0; i < 4; i++){
        int m = m0 + wrow*32 + r*16 + q*4 + i;
        float gv = acc1[r][c][i], u = acc2[r][c][i];
        float sig = 1.0f / (1.0f + __expf(-gv));
        ffh[m*FF + col] = (__bf16)(gv * sig * u);
      }
    }
  }
}

// ---------------- FFN down + residual + final store (K=1024, 4x BK=256) ----------------
__global__ __launch_bounds__(256) void ffn2_kernel(const __bf16* __restrict__ ffh,
                                                   const __bf16* __restrict__ W3T,
                                                   const float* __restrict__ h,
                                                   const unsigned int* __restrict__ tagp,
                                                   void* __restrict__ outp){
  __shared__ __align__(16) __bf16 As[64][256];
  __shared__ __align__(16) __bf16 Bs[64][256];
  int m0 = blockIdx.x*64, n0 = blockIdx.y*64;
  GEMM_PROLOGUE
  #pragma unroll
  for (int k0 = 0; k0 < FF; k0 += 256){
    if (k0) __syncthreads();
    stage256(ffh + m0*FF + k0, FF, &As[0][0]);
    stage256(W3T + n0*FF + k0, FF, &Bs[0][0]);
    __syncthreads();
    mfma256(&As[0][0], &Bs[0][0], acc, wrow, wcol, q, ln);
  }
  bool isf32 = (*tagp == 0x3F800000u);
  #pragma unroll
  for (int c = 0; c < 2; c++){
    int col = n0 + wcol*32 + c*16 + ln;
    #pragma unroll
    for (int r = 0; r < 2; r++){
      #pragma unroll
      for (int i = 0; i < 4; i++){
        int m = m0 + wrow*32 + r*16 + q*4 + i;
        int idx = m*D + col;
        float val = acc[r][c][i] + h[idx];
        if (isf32) ((float*)outp)[idx] = val;
        else       ((__bf16*)outp)[idx] = (__bf16)val;
      }
    }
  }
}

// ---------------- launcher ----------------
extern "C" void kernel_launch(void* const* d_in, const int* in_sizes, int n_in,
                              void* d_out, int out_size, void* d_ws, size_t ws_size,
                              hipStream_t stream){
  char* ws = (char*)d_ws;
  float*  X    = (float*)(ws);                       // 2 MB
  float*  VEC  = (float*)(ws + 2097152);             // 6 KB (pad to 8 KB)
  __bf16* WT   = (__bf16*)(ws + 2097152 + 8192);     // 2 MB
  __bf16* XN   = (__bf16*)(ws + 4202496);            // 1 MB
  __bf16* Qb   = (__bf16*)(ws + 5251072);            // 1 MB
  __bf16* Kb   = Qb + NTOK*D;                        // 1 MB
  __bf16* VTb  = Kb + NTOK*D;                        // 1 MB (transposed V)
  __bf16* ATT  = (__bf16*)(ws + 11542528);           // 1 MB
  float*  Hb   = (float*)(ws + 12591104);            // 2 MB
  __bf16* Yb   = (__bf16*)(ws + 14688256);           // 1 MB
  __bf16* FFH  = (__bf16*)Qb;                        // reuse q/k/vt region after attention

  const unsigned int* tagp = (const unsigned int*)d_in[1];

  MiscArgs ma;
  ma.x = d_in[0];
  ma.vec[0] = d_in[1]; ma.vec[1] = d_in[2]; ma.vec[2] = d_in[4];
  ma.vec[3] = d_in[6]; ma.vec[4] = d_in[8]; ma.vec[5] = d_in[10];

  TPArgs ta;
  ta.src[0] = d_in[3];  ta.src[1] = d_in[5];  ta.src[2] = d_in[7];
  ta.src[3] = d_in[9];  ta.src[4] = d_in[11]; ta.src[5] = d_in[12];
  ta.src[6] = d_in[13];

  prep_kernel<<<3073, 256, 0, stream>>>(ma, ta, X, VEC, WT, XN, tagp);
  qkv_kernel<<<dim3(NTOK/64, 12), 256, 0, stream>>>(XN, WT, VEC, Qb, Kb, VTb);
  attn_kernel<<<dim3(128, 2), 256, 0, stream>>>(Qb, Kb, VTb, ATT);
  oproj_kernel<<<dim3(NTOK/64, 4), 256, 0, stream>>>(ATT, WT + 196608, VEC, X, Hb);
  rmsnorm_kernel<<<NTOK, 256, 0, stream>>>(Hb, VEC + 256, Yb);
  ffn1_kernel<<<dim3(NTOK/64, 16), 256, 0, stream>>>(Yb, WT + 262144, WT + 524288, FFH);
  ffn2_kernel<<<dim3(NTOK/64, 4), 256, 0, stream>>>(FFH, WT + 786432, Hb, tagp, d_out);
}